// Round 5
// baseline (1421.668 us; speedup 1.0000x reference)
//
#include <hip/hip_runtime.h>
#include <hip/hip_bf16.h>

typedef __hip_bfloat16 bf16;

#define WSZ 5
#define NWIN 25
#define CC 48
#define C3 144
#define NHEAD 3
#define HD 16
#define HDIM 400
#define NWH 80
#define SH 2

__device__ __forceinline__ float b2f(bf16 x) { return __bfloat162float(x); }

__device__ __forceinline__ float ldx(const void* p, int f32, int i) {
    if (f32) return ((const float*)p)[i];
    return b2f(((const bf16*)p)[i]);
}

// per-input dtype sniff: flags[i]=1 -> f32, 0 -> bf16 (insurance; evidence says all f32)
__global__ void sniff6(const unsigned* a0, const unsigned* a1, const unsigned* a2,
                       const unsigned* a3, const unsigned* a4, const unsigned* a5,
                       int* flags) {
    int w = threadIdx.x >> 6, lane = threadIdx.x & 63;
    const unsigned* p = (w == 0) ? a0 : (w == 1) ? a1 : (w == 2) ? a2
                      : (w == 3) ? a3 : (w == 4) ? a4 : a5;
    unsigned word = p[lane];
    int bad = (((word >> 7) & 0xFFu) >= 0x90u) ? 1 : 0;   // low-half-as-bf16 exponent huge
    int one = (word == 0x3F800000u) ? 1 : 0;               // f32 literal 1.0 (ln_g=ones)
    unsigned long long mb = __ballot(bad);
    unsigned long long mo = __ballot(one);
    if (lane == 0) flags[w] = (__popcll(mb) > 8 || __popcll(mo) > 32) ? 1 : 0;
}

// One 256-thread block per window. Fully fused; all-f32 internals; f32 output.
__global__ __launch_bounds__(256) void swin_window_kernel(
    const void* __restrict__ lr_v, const void* __restrict__ ref_v,
    const void* __restrict__ qkv_w_v, const void* __restrict__ qkv_b_v,
    const void* __restrict__ ln_g_v, const void* __restrict__ ln_b_v,
    float* __restrict__ out, const int* __restrict__ flags)
{
    __shared__ __align__(16) float s_wf[CC][148];     // 28416 B
    __shared__ __align__(16) float s_pool[2400];      // 9600 B: s_x [2][25][48] then s_att [3][25][25]
    __shared__ __align__(16) float s_y[2][NWIN][145]; // 29000 B
    __shared__ __align__(16) float s_x1[NHEAD][NWIN][HD]; // 4800 B
    __shared__ float s_bias[C3], s_g[C3], s_b[C3];    // 1728 B
    // total 73544 B -> 2 blocks/CU

#define S_X(br,n,c)  s_pool[(((br) * NWIN + (n)) * CC) + (c)]
#define S_ATT(h,n,m) s_pool[(((h) * NWIN + (n)) * NWIN) + (m)]

    const int tid = threadIdx.x;
    const int wid = blockIdx.x;
    const int b   = wid / (NWH * NWH);
    const int r   = wid % (NWH * NWH);
    const int bh  = r / NWH;
    const int bw  = r % NWH;

    const int fLR = flags[0], fRF = flags[1], fW = flags[2];
    const int fB  = flags[3], fG  = flags[4], fBe = flags[5];

    // ---- params + weights ----
    for (int i = tid; i < C3; i += 256) {
        s_bias[i] = ldx(qkv_b_v, fB, i);
        s_g[i]    = ldx(ln_g_v,  fG, i);
        s_b[i]    = ldx(ln_b_v,  fBe, i);
    }
    for (int i = tid; i < CC * C3; i += 256) {
        s_wf[i / C3][i % C3] = ldx(qkv_w_v, fW, i);
    }

    // ---- gather the two shifted windows ----
    if (fLR && fRF) {
        // fast path: float4 loads (pixel rows are 16B-aligned: 48 f32 = 192 B)
        for (int i = tid; i < 2 * NWIN * 12; i += 256) {
            int br  = i / (NWIN * 12);
            int rem = i % (NWIN * 12);
            int n = rem / 12, q = rem % 12;
            int wi = n / WSZ, wj = n % WSZ;
            int h = bh * WSZ + wi + SH; if (h >= HDIM) h -= HDIM;
            int w = bw * WSZ + wj + SH; if (w >= HDIM) w -= HDIM;
            const float* src = br ? (const float*)ref_v : (const float*)lr_v;
            size_t pix = ((size_t)(b * HDIM + h) * HDIM + w) * CC;
            float4 v = reinterpret_cast<const float4*>(src + pix)[q];
            float* dst = &S_X(br, n, q * 4);
            dst[0] = v.x; dst[1] = v.y; dst[2] = v.z; dst[3] = v.w;
        }
    } else {
        for (int i = tid; i < 2 * NWIN * CC; i += 256) {
            int br  = i / (NWIN * CC);
            int rem = i % (NWIN * CC);
            int n = rem / CC, c = rem % CC;
            int wi = n / WSZ, wj = n % WSZ;
            int h = bh * WSZ + wi + SH; if (h >= HDIM) h -= HDIM;
            int w = bw * WSZ + wj + SH; if (w >= HDIM) w -= HDIM;
            int gidx = ((b * HDIM + h) * HDIM + w) * CC + c;
            S_X(br, n, c) = br ? ldx(ref_v, fRF, gidx) : ldx(lr_v, fLR, gidx);
        }
    }
    __syncthreads();

    // ---- projection: y[br][n][j] = x[br][n][:] . W[:][j] + bias[j] ----
    for (int idx = tid; idx < 2 * NWIN * 36; idx += 256) {
        int br  = idx / 900;
        int rem = idx % 900;
        int n   = rem / 36;
        int j0  = (rem % 36) * 4;
        float xr[CC];
        const float4* xv = reinterpret_cast<const float4*>(&S_X(br, n, 0));
        #pragma unroll
        for (int q = 0; q < 12; ++q) {
            float4 v = xv[q];
            xr[q * 4 + 0] = v.x; xr[q * 4 + 1] = v.y;
            xr[q * 4 + 2] = v.z; xr[q * 4 + 3] = v.w;
        }
        float a0 = s_bias[j0], a1 = s_bias[j0 + 1], a2 = s_bias[j0 + 2], a3 = s_bias[j0 + 3];
        #pragma unroll
        for (int c = 0; c < CC; ++c) {
            const float4 wv = *reinterpret_cast<const float4*>(&s_wf[c][j0]);
            a0 += xr[c] * wv.x; a1 += xr[c] * wv.y;
            a2 += xr[c] * wv.z; a3 += xr[c] * wv.w;
        }
        s_y[br][n][j0]     = a0;
        s_y[br][n][j0 + 1] = a1;
        s_y[br][n][j0 + 2] = a2;
        s_y[br][n][j0 + 3] = a3;
    }
    __syncthreads();

    // ---- LayerNorm over 144 channels, one thread per (br,n) row ----
    if (tid < 2 * NWIN) {
        int br = tid / NWIN, n = tid % NWIN;
        float s = 0.f, sq = 0.f;
        for (int j = 0; j < C3; ++j) {
            float v = s_y[br][n][j];
            s += v; sq += v * v;
        }
        float mu  = s * (1.f / 144.f);
        float var = sq * (1.f / 144.f) - mu * mu;
        float rs  = rsqrtf(var + 1e-5f);
        for (int j = 0; j < C3; ++j) {
            float v = s_y[br][n][j];
            s_y[br][n][j] = (v - mu) * rs * s_g[j] + s_b[j];
        }
    }
    __syncthreads();

    // ---- softmax over the 25 window positions, per (br, channel j) ----
    for (int idx = tid; idx < 2 * C3; idx += 256) {
        int br = idx / C3, j = idx % C3;
        float mx = -1e30f;
        #pragma unroll
        for (int n = 0; n < NWIN; ++n) mx = fmaxf(mx, s_y[br][n][j]);
        float sum = 0.f;
        #pragma unroll
        for (int n = 0; n < NWIN; ++n) {
            float e = __expf(s_y[br][n][j] - mx);
            sum += e;
            s_y[br][n][j] = e;
        }
        float inv = 1.f / sum;
        #pragma unroll
        for (int n = 0; n < NWIN; ++n) s_y[br][n][j] *= inv;
    }
    __syncthreads();

    // ---- attn1[h][n][m] = q_lr[h][n][:] . k_ref[h][m][:] ----
    for (int idx = tid; idx < NHEAD * NWIN * NWIN; idx += 256) {
        int h = idx / 625, rem = idx % 625, n = rem / NWIN, m = rem % NWIN;
        const float* qrow = &s_y[0][n][h * HD];
        const float* krow = &s_y[1][m][CC + h * HD];
        float acc = 0.f;
        #pragma unroll
        for (int d = 0; d < HD; ++d) acc += qrow[d] * krow[d];
        S_ATT(h, n, m) = acc;
    }
    __syncthreads();

    // ---- x1 = attn1 . v_ref ----
    for (int idx = tid; idx < NHEAD * NWIN * HD; idx += 256) {
        int h = idx / 400, rem = idx % 400, n = rem / HD, d = rem % HD;
        float acc = 0.f;
        #pragma unroll
        for (int m = 0; m < NWIN; ++m)
            acc += S_ATT(h, n, m) * s_y[1][m][2 * CC + h * HD + d];
        s_x1[h][n][d] = acc;
    }
    __syncthreads();

    // ---- attn2[h][n][m] = q_ref[h][n][:] . k_lr[h][m][:] ----
    for (int idx = tid; idx < NHEAD * NWIN * NWIN; idx += 256) {
        int h = idx / 625, rem = idx % 625, n = rem / NWIN, m = rem % NWIN;
        const float* qrow = &s_y[1][n][h * HD];
        const float* krow = &s_y[0][m][CC + h * HD];
        float acc = 0.f;
        #pragma unroll
        for (int d = 0; d < HD; ++d) acc += qrow[d] * krow[d];
        S_ATT(h, n, m) = acc;
    }
    __syncthreads();

    // ---- x2 = attn2 . x1; scatter (window_reverse + roll(+2,+2)) as f32 float4 ----
    for (int idx = tid; idx < NWIN * 12; idx += 256) {
        int n = idx / 12, q = idx % 12;
        int c0 = q * 4, h = c0 / HD, d0 = c0 % HD;   // 4 consecutive d, same head
        float a0 = 0.f, a1 = 0.f, a2 = 0.f, a3 = 0.f;
        #pragma unroll
        for (int m = 0; m < NWIN; ++m) {
            float w = S_ATT(h, n, m);
            const float* xr = &s_x1[h][m][d0];
            a0 += w * xr[0]; a1 += w * xr[1]; a2 += w * xr[2]; a3 += w * xr[3];
        }
        int wi = n / WSZ, wj = n % WSZ;
        int oh = bh * WSZ + wi + SH; if (oh >= HDIM) oh -= HDIM;
        int ow = bw * WSZ + wj + SH; if (ow >= HDIM) ow -= HDIM;
        float4 v = make_float4(a0, a1, a2, a3);
        reinterpret_cast<float4*>(&out[((size_t)((b * HDIM + oh) * HDIM + ow)) * CC + c0])[0] = v;
    }
#undef S_X
#undef S_ATT
}

// Output 1 = ref_patch passthrough, f32 -> f32 (or bf16 -> f32 fallback).
__global__ void copy_ref_kernel(const void* __restrict__ src, float* __restrict__ dst,
                                const int* __restrict__ flags, long long n4) {
    long long i = (long long)blockIdx.x * blockDim.x + threadIdx.x;
    const long long stride = (long long)gridDim.x * blockDim.x;
    if (flags[1]) {
        const float4* s = (const float4*)src;
        float4* d = (float4*)dst;
        for (; i < n4; i += stride) d[i] = s[i];
    } else {
        const bf16* s = (const bf16*)src;
        for (; i < n4; i += stride) {
            float4 v = make_float4(b2f(s[4 * i]), b2f(s[4 * i + 1]),
                                   b2f(s[4 * i + 2]), b2f(s[4 * i + 3]));
            reinterpret_cast<float4*>(dst)[i] = v;
        }
    }
}

extern "C" void kernel_launch(void* const* d_in, const int* in_sizes, int n_in,
                              void* d_out, int out_size, void* d_ws, size_t ws_size,
                              hipStream_t stream) {
    const void* lr    = d_in[0];
    const void* ref   = d_in[1];
    const void* qkv_w = d_in[2];
    const void* qkv_b = d_in[3];
    const void* ln_g  = d_in[4];
    const void* ln_b  = d_in[5];
    float* out = (float*)d_out;
    int* flags = (int*)d_ws;

    sniff6<<<1, 384, 0, stream>>>((const unsigned*)lr, (const unsigned*)ref,
                                  (const unsigned*)qkv_w, (const unsigned*)qkv_b,
                                  (const unsigned*)ln_g, (const unsigned*)ln_b, flags);

    const int n_windows = 4 * NWH * NWH;  // 25600
    swin_window_kernel<<<n_windows, 256, 0, stream>>>(lr, ref, qkv_w, qkv_b, ln_g, ln_b, out, flags);

    const size_t elems0 = (size_t)out_size / 2;      // 30,720,000 floats
    const long long n4 = (long long)(elems0 / 4);    // float4 groups
    copy_ref_kernel<<<2048, 256, 0, stream>>>(ref, out + elems0, flags, n4);
}

// Round 6
// 812.221 us; speedup vs baseline: 1.7503x; 1.7503x over previous
//
#include <hip/hip_runtime.h>
#include <hip/hip_bf16.h>

typedef __hip_bfloat16 bf16;

#define WSZ 5
#define NWIN 25
#define CC 48
#define C3 144
#define NHEAD 3
#define HD 16
#define HDIM 400
#define NWH 80
#define SH 2
#define YW 73   // u32 words per s_y row (146 bf16 >= 144 + pad; odd word stride -> conflict-free)

__device__ __forceinline__ void unpack2(unsigned u, float& a, float& b) {
    union { unsigned i; float f; } x, y;
    x.i = u << 16;
    y.i = u & 0xffff0000u;
    a = x.f; b = y.f;
}

__device__ __forceinline__ unsigned pack2(float lo, float hi) {
    union { bf16 b[2]; unsigned u; } p;
    p.b[0] = __float2bfloat16(lo);
    p.b[1] = __float2bfloat16(hi);
    return p.u;
}

// One 256-thread block (4 waves) per window.
// Wave w owns j-columns [36w, 36w+36); lane l = br*32 + n owns window row (br, n).
// Projection reads W/bias/ln params via wave-uniform addresses -> scalar loads.
__global__ __launch_bounds__(256, 4) void swin_fused(
    const float* __restrict__ lr, const float* __restrict__ ref,
    const float* __restrict__ qkv_w, const float* __restrict__ qkv_b,
    const float* __restrict__ ln_g, const float* __restrict__ ln_b,
    float* __restrict__ out)
{
    __shared__ unsigned s_y[2 * NWIN * YW];        // 14600 B: softmaxed q,k,v as bf16 pairs
    __shared__ float s_att[2][NHEAD][NWIN][26];    // 15600 B: attn1, attn2 (padded rows)
    __shared__ float s_x1[NHEAD][NWIN][HD];        // 4800 B
    __shared__ float s_red[4][2][64];              // 2048 B: LN partial sums
    // total 37048 B -> 4 blocks/CU (LDS); VGPR cap 128 -> 16 waves/CU

    const int tid  = threadIdx.x;
    const int wave = __builtin_amdgcn_readfirstlane(tid >> 6);
    const int lane = tid & 63;
    const int br   = lane >> 5;           // 0 = lr, 1 = ref
    const int nr   = lane & 31;
    const bool act = (nr < NWIN) && (lane < 64);
    const int n    = (nr < NWIN) ? nr : NWIN - 1;   // clamp idle lanes to a valid row

    const int wid = blockIdx.x;
    const int b   = wid / (NWH * NWH);
    const int r   = wid % (NWH * NWH);
    const int bh  = r / NWH;
    const int bw  = r % NWH;

    // ---- gather: each lane loads its pixel row (48 f32) into registers ----
    {
    }
    int wi = n / WSZ, wj = n % WSZ;
    int hh0 = bh * WSZ + wi + SH; if (hh0 >= HDIM) hh0 -= HDIM;
    int ww0 = bw * WSZ + wj + SH; if (ww0 >= HDIM) ww0 -= HDIM;
    const float* src = br ? ref : lr;
    const float4* prow = reinterpret_cast<const float4*>(
        src + ((size_t)(b * HDIM + hh0) * HDIM + ww0) * CC);
    float x[CC];
    #pragma unroll
    for (int q = 0; q < 12; ++q) {
        float4 v = prow[q];
        x[q * 4 + 0] = v.x; x[q * 4 + 1] = v.y;
        x[q * 4 + 2] = v.z; x[q * 4 + 3] = v.w;
    }

    // ---- projection: y[row][j] for this wave's 36 columns (W via scalar loads) ----
    const int jbase = wave * 36;
    float y[9][4];
    #pragma unroll
    for (int g = 0; g < 9; ++g) {
        const int j0 = jbase + g * 4;
        const float4 bias = *reinterpret_cast<const float4*>(qkv_b + j0);
        float a0 = bias.x, a1 = bias.y, a2 = bias.z, a3 = bias.w;
        #pragma unroll
        for (int c = 0; c < CC; ++c) {
            const float4 wv = *reinterpret_cast<const float4*>(qkv_w + c * C3 + j0);
            a0 += x[c] * wv.x; a1 += x[c] * wv.y;
            a2 += x[c] * wv.z; a3 += x[c] * wv.w;
        }
        y[g][0] = a0; y[g][1] = a1; y[g][2] = a2; y[g][3] = a3;
    }

    // ---- LayerNorm over 144: partial sums cross-wave via LDS ----
    {
        float s = 0.f, sq = 0.f;
        #pragma unroll
        for (int g = 0; g < 9; ++g)
            #pragma unroll
            for (int k = 0; k < 4; ++k) { float v = y[g][k]; s += v; sq += v * v; }
        s_red[wave][0][lane] = s;
        s_red[wave][1][lane] = sq;
    }
    __syncthreads();
    {
        float S = 0.f, SQ = 0.f;
        #pragma unroll
        for (int ww = 0; ww < 4; ++ww) { S += s_red[ww][0][lane]; SQ += s_red[ww][1][lane]; }
        float mu  = S * (1.f / 144.f);
        float var = SQ * (1.f / 144.f) - mu * mu;
        float rs  = rsqrtf(var + 1e-5f);
        #pragma unroll
        for (int g = 0; g < 9; ++g) {
            const int j0 = jbase + g * 4;
            const float4 gg = *reinterpret_cast<const float4*>(ln_g + j0);
            const float4 bb = *reinterpret_cast<const float4*>(ln_b + j0);
            y[g][0] = (y[g][0] - mu) * rs * gg.x + bb.x;
            y[g][1] = (y[g][1] - mu) * rs * gg.y + bb.y;
            y[g][2] = (y[g][2] - mu) * rs * gg.z + bb.z;
            y[g][3] = (y[g][3] - mu) * rs * gg.w + bb.w;
        }
    }
    // idle lanes must not perturb the cross-lane softmax
    if (!act) {
        #pragma unroll
        for (int g = 0; g < 9; ++g)
            #pragma unroll
            for (int k = 0; k < 4; ++k) y[g][k] = -1e30f;
    }

    // ---- softmax over the 25 window positions: shfl_xor within 32-lane halves ----
    #pragma unroll
    for (int g = 0; g < 9; ++g) {
        #pragma unroll
        for (int k = 0; k < 4; ++k) {
            float v = y[g][k];
            float mx = v;
            #pragma unroll
            for (int off = 16; off >= 1; off >>= 1)
                mx = fmaxf(mx, __shfl_xor(mx, off, 32));
            float e = __expf(v - mx);
            float ss = e;
            #pragma unroll
            for (int off = 16; off >= 1; off >>= 1)
                ss += __shfl_xor(ss, off, 32);
            y[g][k] = e / ss;
        }
    }

    // ---- write softmaxed q,k,v to LDS as bf16 pairs ----
    if (act) {
        const int rowbase = (br * NWIN + n) * YW + wave * 18;
        #pragma unroll
        for (int g = 0; g < 9; ++g) {
            s_y[rowbase + g * 2]     = pack2(y[g][0], y[g][1]);
            s_y[rowbase + g * 2 + 1] = pack2(y[g][2], y[g][3]);
        }
    }
    __syncthreads();

    // ---- attn1 & attn2 in one phase ----
    // attn[a][h][n][m]: a=0: q_lr[n] . k_ref[m]; a=1: q_ref[n] . k_lr[m]
    for (int idx = tid; idx < 2 * NHEAD * NWIN * NWIN; idx += 256) {
        int a   = idx / 1875;
        int rem = idx % 1875;
        int hh  = rem / 625;
        int nn  = (rem / 25) % 25;
        int mm  = rem % 25;
        const unsigned* qw = s_y + ((a ? NWIN : 0) + nn) * YW + 8 * hh;
        const unsigned* kw = s_y + ((a ? 0 : NWIN) + mm) * YW + 24 + 8 * hh;
        float acc = 0.f;
        #pragma unroll
        for (int t = 0; t < 8; ++t) {
            float q0, q1, k0, k1;
            unpack2(qw[t], q0, q1);
            unpack2(kw[t], k0, k1);
            acc += q0 * k0 + q1 * k1;
        }
        s_att[a][hh][nn][mm] = acc;
    }
    __syncthreads();

    // ---- x1[h][n][d] = attn1[h][n][:] . v_ref[:][h][d] ----
    for (int idx = tid; idx < NHEAD * NWIN * HD; idx += 256) {
        int hh  = idx / 400;
        int rem = idx % 400;
        int nn  = rem / HD;
        int dd  = rem % HD;
        float acc = 0.f;
        #pragma unroll
        for (int m = 0; m < NWIN; ++m) {
            unsigned u = s_y[(NWIN + m) * YW + 48 + 8 * hh + (dd >> 1)];
            float v0, v1; unpack2(u, v0, v1);
            acc += s_att[0][hh][nn][m] * ((dd & 1) ? v1 : v0);
        }
        s_x1[hh][nn][dd] = acc;
    }
    __syncthreads();

    // ---- x2 = attn2 . x1; scatter (window_reverse + roll(+2,+2)) ----
    for (int idx = tid; idx < NWIN * 12; idx += 256) {
        int nn = idx / 12, q = idx % 12;
        int c0 = q * 4, hh = c0 / HD, d0 = c0 % HD;
        float a0 = 0.f, a1 = 0.f, a2 = 0.f, a3 = 0.f;
        #pragma unroll
        for (int m = 0; m < NWIN; ++m) {
            float t = s_att[1][hh][nn][m];
            const float* xr = &s_x1[hh][m][d0];
            a0 += t * xr[0]; a1 += t * xr[1]; a2 += t * xr[2]; a3 += t * xr[3];
        }
        int wi2 = nn / WSZ, wj2 = nn % WSZ;
        int oh = bh * WSZ + wi2 + SH; if (oh >= HDIM) oh -= HDIM;
        int ow = bw * WSZ + wj2 + SH; if (ow >= HDIM) ow -= HDIM;
        reinterpret_cast<float4*>(&out[((size_t)((b * HDIM + oh) * HDIM + ow)) * CC + c0])[0]
            = make_float4(a0, a1, a2, a3);
    }
}

// Output 1 = ref_patch passthrough (f32 -> f32).
__global__ void copy_ref_kernel(const float4* __restrict__ src, float4* __restrict__ dst,
                                long long n4) {
    long long i = (long long)blockIdx.x * blockDim.x + threadIdx.x;
    const long long stride = (long long)gridDim.x * blockDim.x;
    for (; i < n4; i += stride) dst[i] = src[i];
}

extern "C" void kernel_launch(void* const* d_in, const int* in_sizes, int n_in,
                              void* d_out, int out_size, void* d_ws, size_t ws_size,
                              hipStream_t stream) {
    const float* lr    = (const float*)d_in[0];
    const float* ref   = (const float*)d_in[1];
    const float* qkv_w = (const float*)d_in[2];
    const float* qkv_b = (const float*)d_in[3];
    const float* ln_g  = (const float*)d_in[4];
    const float* ln_b  = (const float*)d_in[5];
    float* out = (float*)d_out;

    const int n_windows = 4 * NWH * NWH;  // 25600
    swin_fused<<<n_windows, 256, 0, stream>>>(lr, ref, qkv_w, qkv_b, ln_g, ln_b, out);

    const size_t elems0 = (size_t)out_size / 2;      // 30,720,000 floats
    const long long n4 = (long long)(elems0 / 4);
    copy_ref_kernel<<<2048, 256, 0, stream>>>(
        (const float4*)ref, (float4*)(out + elems0), n4);
}

// Round 7
// 329.680 us; speedup vs baseline: 4.3123x; 2.4637x over previous
//
#include <hip/hip_runtime.h>
#include <hip/hip_bf16.h>

typedef __hip_bfloat16 hbf16;
typedef unsigned short ushort_t;
typedef __attribute__((ext_vector_type(8))) short bf16x8;
typedef __attribute__((ext_vector_type(4))) float f32x4;

#define WSZ 5
#define NWIN 25
#define CC 48
#define C3 144
#define HD 16
#define HDIM 400
#define NWH 80
#define SH 2
#define WPB 8          // windows per block
#define YW 152         // s_y row stride in bf16 elems (304 B, mult 16, bank-spread)
#define WTW 56         // s_wT row stride (112 B, mult 16, bank-spread)
#define PW 40          // s_P / s_vT / s_x1T row stride (80 B, mult 16, bank-spread)

__device__ __forceinline__ ushort_t f2b(float x) {
    union { hbf16 h; ushort_t u; } c;
    c.h = __float2bfloat16(x);
    return c.u;
}
__device__ __forceinline__ float b2f_u(unsigned u) {
    union { unsigned i; float f; } c;
    c.i = u << 16;
    return c.f;
}
__device__ __forceinline__ unsigned pk2(float lo, float hi) {
    return ((unsigned)f2b(hi) << 16) | f2b(lo);
}

__global__ __launch_bounds__(256, 3) void swin_mfma(
    const float* __restrict__ lr, const float* __restrict__ ref,
    const float* __restrict__ qkv_w, const float* __restrict__ qkv_b,
    const float* __restrict__ ln_g, const float* __restrict__ ln_b,
    float* __restrict__ out)
{
    __shared__ __align__(16) ushort_t s_wT[C3 * WTW];     // W^T bf16 [col][k], 16128 B
    __shared__ __align__(16) ushort_t s_y[64 * YW];       // softmaxed y bf16 [pr][col], 19456 B
    __shared__ __align__(16) ushort_t s_vT[3 * 16 * PW];  // v_ref^T per head [dv][m], 3840 B
    __shared__ __align__(16) ushort_t s_x1T[3 * 16 * PW]; // x1^T per head [dv][m], 3840 B
    __shared__ __align__(16) ushort_t s_P[3 * 32 * PW];   // P per head [n][m], 7680 B
    __shared__ float s_gb[3 * C3];                        // bias | ln_g | ln_b, 1728 B
    // total 52672 B -> 3 blocks/CU

    const int tid  = threadIdx.x;
    const int wave = tid >> 6;
    const int lane = tid & 63;
    const int lm   = lane & 15;   // fragment row/col index
    const int g    = lane >> 4;   // k-group

    // ---- per-block staging (once per 8 windows) ----
    for (int i = tid; i < CC * C3; i += 256) {
        int c = i / C3, j = i % C3;
        s_wT[j * WTW + c] = f2b(qkv_w[i]);
    }
    for (int i = tid; i < C3; i += 256) {
        s_gb[i]           = qkv_b[i];
        s_gb[C3 + i]      = ln_g[i];
        s_gb[2 * C3 + i]  = ln_b[i];
    }
    for (int i = tid; i < 3 * 16 * PW; i += 256) { s_vT[i] = 0; s_x1T[i] = 0; }
    for (int i = tid; i < 3 * 32 * PW; i += 256) { s_P[i] = 0; }
    __syncthreads();

    const bf16x8 z8 = {0, 0, 0, 0, 0, 0, 0, 0};
    const f32x4  z4 = {0.f, 0.f, 0.f, 0.f};

    for (int it = 0; it < WPB; ++it) {
        const int wid = blockIdx.x * WPB + it;
        const int b   = wid / (NWH * NWH);
        const int rr  = wid % (NWH * NWH);
        const int bh  = rr / NWH;
        const int bw  = rr % NWH;

        // ---- X fragments directly from global (A-frag layout: row=lm, k=8g+j) ----
        const int pr = 16 * wave + lm;                  // padded M-row
        const bool vrow = (pr < 25) || (pr >= 32 && pr < 57);
        bf16x8 xa = z8, xb = z8;
        int n_row = (pr < 25) ? pr : pr - 32;
        {
            int wi = n_row / WSZ, wj = n_row % WSZ;
            int hh = bh * WSZ + wi + SH; if (hh >= HDIM) hh -= HDIM;
            int ww = bw * WSZ + wj + SH; if (ww >= HDIM) ww -= HDIM;
            const float* src = (pr < 32) ? lr : ref;
            const float* prow = src + ((size_t)(b * HDIM + hh) * HDIM + ww) * CC;
            if (vrow) {
                const float4* p4 = reinterpret_cast<const float4*>(prow);
                float4 u = p4[2 * g], v = p4[2 * g + 1];        // k = 8g..8g+7
                xa[0]=f2b(u.x); xa[1]=f2b(u.y); xa[2]=f2b(u.z); xa[3]=f2b(u.w);
                xa[4]=f2b(v.x); xa[5]=f2b(v.y); xa[6]=f2b(v.z); xa[7]=f2b(v.w);
                if (g < 2) {                                    // k = 32+8g..39+8g
                    float4 u2 = p4[8 + 2 * g], v2 = p4[9 + 2 * g];
                    xb[0]=f2b(u2.x); xb[1]=f2b(u2.y); xb[2]=f2b(u2.z); xb[3]=f2b(u2.w);
                    xb[4]=f2b(v2.x); xb[5]=f2b(v2.y); xb[6]=f2b(v2.z); xb[7]=f2b(v2.w);
                }
            }
        }

        // ---- projection: acc[t] = bias + X*W (two K-steps of 32) ----
        f32x4 acc[9];
        const int ko2 = 32 + 8 * (g & 1);   // wrapped k-offset for step 2 (xb==0 masks g>=2)
        #pragma unroll
        for (int t = 0; t < 9; ++t) {
            const int col = 16 * t + lm;
            float bias = s_gb[col];
            f32x4 a = {bias, bias, bias, bias};
            bf16x8 w1 = *reinterpret_cast<const bf16x8*>(&s_wT[col * WTW + 8 * g]);
            a = __builtin_amdgcn_mfma_f32_16x16x32_bf16(xa, w1, a, 0, 0, 0);
            bf16x8 w2 = *reinterpret_cast<const bf16x8*>(&s_wT[col * WTW + ko2]);
            a = __builtin_amdgcn_mfma_f32_16x16x32_bf16(xb, w2, a, 0, 0, 0);
            acc[t] = a;
        }

        // ---- LayerNorm in-fragment (reduce over 16-lane group = all 144 cols) ----
        float mu[4], rs[4];
        #pragma unroll
        for (int r2 = 0; r2 < 4; ++r2) {
            float s = 0.f, sq = 0.f;
            #pragma unroll
            for (int t = 0; t < 9; ++t) { float v = acc[t][r2]; s += v; sq += v * v; }
            #pragma unroll
            for (int off = 8; off >= 1; off >>= 1) {
                s  += __shfl_xor(s, off);
                sq += __shfl_xor(sq, off);
            }
            float m = s * (1.f / 144.f);
            mu[r2] = m;
            rs[r2] = rsqrtf(sq * (1.f / 144.f) - m * m + 1e-5f);
        }

        // ---- store y (bf16) rows: row = 16*wave + 4*g + r2, col = 16t+lm ----
        const int prb = 16 * wave + 4 * g;
        #pragma unroll
        for (int t = 0; t < 9; ++t) {
            const int col = 16 * t + lm;
            const float gg = s_gb[C3 + col], bb = s_gb[2 * C3 + col];
            #pragma unroll
            for (int r2 = 0; r2 < 4; ++r2) {
                const int prow2 = prb + r2;
                const bool ok = (prow2 < 25) || (prow2 >= 32 && prow2 < 57);
                float yv = (acc[t][r2] - mu[r2]) * rs[r2] * gg + bb;
                ushort_t hv = ok ? f2b(yv) : (ushort_t)0;
                s_y[prow2 * YW + col] = hv;
            }
        }
        __syncthreads();

        // ---- softmax over 25 positions per (br, col); 72 items per wave ----
        #pragma unroll
        for (int ii = 0; ii < 2; ++ii) {
            const int item = wave * 72 + ii * 64 + lane;
            if (ii == 0 || lane < 8) {
                const int br  = item / C3;
                const int col = item % C3;
                const int base = br ? 32 : 0;
                float v[25];
                float mx = -1e30f;
                #pragma unroll
                for (int j = 0; j < 25; ++j) {
                    v[j] = b2f_u((unsigned)s_y[(base + j) * YW + col]);
                    mx = fmaxf(mx, v[j]);
                }
                float sum = 0.f;
                #pragma unroll
                for (int j = 0; j < 25; ++j) { v[j] = __expf(v[j] - mx); sum += v[j]; }
                float inv = 1.f / sum;
                #pragma unroll
                for (int j = 0; j < 25; ++j)
                    s_y[(base + j) * YW + col] = f2b(v[j] * inv);
            }
        }
        __syncthreads();

        // ---- v_ref^T side-copy for PV1 A-frags ----
        // (re-read softmaxed v of ref rows; cols 96..143)
        for (int i = tid; i < 25 * CC; i += 256) {
            int m = i / CC, c = i % CC;          // c in [0,48): v-channel
            int h2 = c >> 4, dv = c & 15;
            s_vT[h2 * (16 * PW) + dv * PW + m] = s_y[(32 + m) * YW + 96 + c];
        }
        __syncthreads();

        // ---- attention: wave h < 3 handles head h ----
        if (wave < 3) {
            const int h = wave;
            const int ko = 8 * (g & 1);          // d-offset within head (g>=2 masked to 0)
            // QK1: attn1[n][m] = q_lr[n].k_ref[m];  A=k_ref rows, B=q_lr cols
            f32x4 p1[2][2];
            bf16x8 ka0, ka1, qb0, qb1;
            {
                bf16x8 t0 = *reinterpret_cast<const bf16x8*>(&s_y[(32 + lm) * YW + CC + 16 * h + ko]);
                bf16x8 t1 = *reinterpret_cast<const bf16x8*>(&s_y[(48 + lm) * YW + CC + 16 * h + ko]);
                ka0 = (g < 2) ? t0 : z8;  ka1 = (g < 2) ? t1 : z8;
                bf16x8 t2 = *reinterpret_cast<const bf16x8*>(&s_y[lm * YW + 16 * h + ko]);
                bf16x8 t3 = *reinterpret_cast<const bf16x8*>(&s_y[(16 + lm) * YW + 16 * h + ko]);
                qb0 = (g < 2) ? t2 : z8;  qb1 = (g < 2) ? t3 : z8;
            }
            p1[0][0] = __builtin_amdgcn_mfma_f32_16x16x32_bf16(ka0, qb0, z4, 0, 0, 0);
            p1[0][1] = __builtin_amdgcn_mfma_f32_16x16x32_bf16(ka0, qb1, z4, 0, 0, 0);
            p1[1][0] = __builtin_amdgcn_mfma_f32_16x16x32_bf16(ka1, qb0, z4, 0, 0, 0);
            p1[1][1] = __builtin_amdgcn_mfma_f32_16x16x32_bf16(ka1, qb1, z4, 0, 0, 0);
            // store P1[n][m] (bf16) : n = 16*nt+lm, m = 16*mt+4g+r
            #pragma unroll
            for (int mt = 0; mt < 2; ++mt)
                #pragma unroll
                for (int nt = 0; nt < 2; ++nt) {
                    uint2 wv;
                    wv.x = pk2(p1[mt][nt][0], p1[mt][nt][1]);
                    wv.y = pk2(p1[mt][nt][2], p1[mt][nt][3]);
                    *reinterpret_cast<uint2*>(&s_P[h * (32 * PW) + (16 * nt + lm) * PW + 16 * mt + 4 * g]) = wv;
                }
            // PV1: x1^T[dv][n] = sum_m v^T[dv][m] * P1[n][m]
            f32x4 x1a[2];
            {
                bf16x8 va = *reinterpret_cast<const bf16x8*>(&s_vT[h * (16 * PW) + lm * PW + 8 * g]);
                bf16x8 pb0 = *reinterpret_cast<const bf16x8*>(&s_P[h * (32 * PW) + lm * PW + 8 * g]);
                bf16x8 pb1 = *reinterpret_cast<const bf16x8*>(&s_P[h * (32 * PW) + (16 + lm) * PW + 8 * g]);
                x1a[0] = __builtin_amdgcn_mfma_f32_16x16x32_bf16(va, pb0, z4, 0, 0, 0);
                x1a[1] = __builtin_amdgcn_mfma_f32_16x16x32_bf16(va, pb1, z4, 0, 0, 0);
            }
            // store x1^T[dv][n]: dv = 4g+r, n = 16*nt+lm
            #pragma unroll
            for (int nt = 0; nt < 2; ++nt)
                #pragma unroll
                for (int r2 = 0; r2 < 4; ++r2)
                    s_x1T[h * (16 * PW) + (4 * g + r2) * PW + 16 * nt + lm] = f2b(x1a[nt][r2]);
            // QK2: attn2[n][m] = q_ref[n].k_lr[m]
            f32x4 p2[2][2];
            {
                bf16x8 t0 = *reinterpret_cast<const bf16x8*>(&s_y[lm * YW + CC + 16 * h + ko]);
                bf16x8 t1 = *reinterpret_cast<const bf16x8*>(&s_y[(16 + lm) * YW + CC + 16 * h + ko]);
                ka0 = (g < 2) ? t0 : z8;  ka1 = (g < 2) ? t1 : z8;
                bf16x8 t2 = *reinterpret_cast<const bf16x8*>(&s_y[(32 + lm) * YW + 16 * h + ko]);
                bf16x8 t3 = *reinterpret_cast<const bf16x8*>(&s_y[(48 + lm) * YW + 16 * h + ko]);
                qb0 = (g < 2) ? t2 : z8;  qb1 = (g < 2) ? t3 : z8;
            }
            p2[0][0] = __builtin_amdgcn_mfma_f32_16x16x32_bf16(ka0, qb0, z4, 0, 0, 0);
            p2[0][1] = __builtin_amdgcn_mfma_f32_16x16x32_bf16(ka0, qb1, z4, 0, 0, 0);
            p2[1][0] = __builtin_amdgcn_mfma_f32_16x16x32_bf16(ka1, qb0, z4, 0, 0, 0);
            p2[1][1] = __builtin_amdgcn_mfma_f32_16x16x32_bf16(ka1, qb1, z4, 0, 0, 0);
            #pragma unroll
            for (int mt = 0; mt < 2; ++mt)
                #pragma unroll
                for (int nt = 0; nt < 2; ++nt) {
                    uint2 wv;
                    wv.x = pk2(p2[mt][nt][0], p2[mt][nt][1]);
                    wv.y = pk2(p2[mt][nt][2], p2[mt][nt][3]);
                    *reinterpret_cast<uint2*>(&s_P[h * (32 * PW) + (16 * nt + lm) * PW + 16 * mt + 4 * g]) = wv;
                }
            // PV2: x2^T[dv'][n] = sum_m x1^T[dv'][m] * P2[n][m]; write out
            {
                bf16x8 xv = *reinterpret_cast<const bf16x8*>(&s_x1T[h * (16 * PW) + lm * PW + 8 * g]);
                #pragma unroll
                for (int nt = 0; nt < 2; ++nt) {
                    bf16x8 pb = *reinterpret_cast<const bf16x8*>(&s_P[h * (32 * PW) + (16 * nt + lm) * PW + 8 * g]);
                    f32x4 x2a = __builtin_amdgcn_mfma_f32_16x16x32_bf16(xv, pb, z4, 0, 0, 0);
                    const int n = 16 * nt + lm;
                    if (n < 25) {
                        int wi = n / WSZ, wj = n % WSZ;
                        int oh = bh * WSZ + wi + SH; if (oh >= HDIM) oh -= HDIM;
                        int ow = bw * WSZ + wj + SH; if (ow >= HDIM) ow -= HDIM;
                        float4 o = make_float4(x2a[0], x2a[1], x2a[2], x2a[3]);
                        *reinterpret_cast<float4*>(
                            &out[((size_t)((b * HDIM + oh) * HDIM + ow)) * CC + 16 * h + 4 * g]) = o;
                    }
                }
            }
        }
        __syncthreads();
    }
}

// Output 1 = ref_patch passthrough (f32 -> f32).
__global__ void copy_ref_kernel(const float4* __restrict__ src, float4* __restrict__ dst,
                                long long n4) {
    long long i = (long long)blockIdx.x * blockDim.x + threadIdx.x;
    const long long stride = (long long)gridDim.x * blockDim.x;
    for (; i < n4; i += stride) dst[i] = src[i];
}

extern "C" void kernel_launch(void* const* d_in, const int* in_sizes, int n_in,
                              void* d_out, int out_size, void* d_ws, size_t ws_size,
                              hipStream_t stream) {
    const float* lr    = (const float*)d_in[0];
    const float* ref   = (const float*)d_in[1];
    const float* qkv_w = (const float*)d_in[2];
    const float* qkv_b = (const float*)d_in[3];
    const float* ln_g  = (const float*)d_in[4];
    const float* ln_b  = (const float*)d_in[5];
    float* out = (float*)d_out;

    const int n_blocks = 4 * NWH * NWH / WPB;   // 3200
    swin_mfma<<<n_blocks, 256, 0, stream>>>(lr, ref, qkv_w, qkv_b, ln_g, ln_b, out);

    const size_t elems0 = (size_t)out_size / 2;      // 30,720,000 floats
    const long long n4 = (long long)(elems0 / 4);
    copy_ref_kernel<<<2048, 256, 0, stream>>>(
        (const float4*)ref, (float4*)(out + elems0), n4);
}